// Round 1
// baseline (251.516 us; speedup 1.0000x reference)
//
#include <hip/hip_runtime.h>
#include <math.h>

#define ROWS 8192
#define NCOL 2048
#define V 32
#define WPB 4                 // waves (rows) per block
#define THREADS (WPB * 64)

// static compare-exchange: ascending, both indices compile-time
__device__ __forceinline__ void ce(float& a, float& b) {
  const float lo = fminf(a, b);
  const float hi = fmaxf(a, b);
  a = lo; b = hi;
}

// med3(a,b,-inf)=min(a,b); med3(a,b,+inf)=max(a,b). One VALU op per
// cross-lane compare-exchange, direction baked into per-pass constant.
__device__ __forceinline__ float ce_dir(float a, float b, float cdir) {
  return __builtin_amdgcn_fmed3f(a, b, cdir);
}

// ---- cross-lane partner fetch x[lane ^ M], cheapest primitive per mask ----
// DPP (pure VALU, no lgkmcnt) for masks expressible as quad_perm / row ops;
// ds_swizzle BitMode (1 DS op, no address VGPR) for xor-4/16/31;
// bpermute (__shfl_xor) only for the single mask-63 pass.
template <int CTRL>
__device__ __forceinline__ float dpp_mov(float x) {
  return __builtin_bit_cast(
      float, __builtin_amdgcn_update_dpp(0, __builtin_bit_cast(int, x),
                                         CTRL, 0xF, 0xF, true));
}

template <int PAT>
__device__ __forceinline__ float swz(float x) {
  return __builtin_bit_cast(
      float, __builtin_amdgcn_ds_swizzle(__builtin_bit_cast(int, x), PAT));
}

template <int M>
__device__ __forceinline__ float lane_xor(float x) {
  if constexpr (M == 1)       return dpp_mov<0xB1>(x);    // quad_perm [1,0,3,2]
  else if constexpr (M == 2)  return dpp_mov<0x4E>(x);    // quad_perm [2,3,0,1]
  else if constexpr (M == 3)  return dpp_mov<0x1B>(x);    // quad_perm [3,2,1,0]
  else if constexpr (M == 7)  return dpp_mov<0x141>(x);   // row_half_mirror
  else if constexpr (M == 8)  return dpp_mov<0x128>(x);   // row_ror:8 == xor-8
  else if constexpr (M == 15) return dpp_mov<0x140>(x);   // row_mirror
  else if constexpr (M == 4)  return swz<0x101F>(x);      // BitMode xor-4
  else if constexpr (M == 16) return swz<0x401F>(x);      // BitMode xor-16
  else if constexpr (M == 31) return swz<0x7C1F>(x);      // BitMode xor-31
  else                        return __shfl_xor(x, M, 64); // M==63: bpermute
}

// cross-lane xor pass over both arrays, same element index, mask M.
// Batched 8-deep per array so DS variants keep >=8 ops in flight.
template <int M>
__device__ __forceinline__ void xpass2(float (&a)[V], float (&b)[V],
                                       float cdir) {
#pragma unroll
  for (int c = 0; c < V; c += 8) {
    float oa[8], ob[8];
#pragma unroll
    for (int u = 0; u < 8; ++u) oa[u] = lane_xor<M>(a[c + u]);
#pragma unroll
    for (int u = 0; u < 8; ++u) ob[u] = lane_xor<M>(b[c + u]);
#pragma unroll
    for (int u = 0; u < 8; ++u) a[c + u] = ce_dir(a[c + u], oa[u], cdir);
#pragma unroll
    for (int u = 0; u < 8; ++u) b[c + u] = ce_dir(b[c + u], ob[u], cdir);
  }
}

// One bitonic merge stage for run length k = 64*KB (KB = 1..32):
// flip pass (partner lane^(2KB-1), elem v^31), xor passes KB/2..1,
// then the in-lane tail j = 16..1. Both arrays per pass for ILP.
template <int KB>
__device__ __forceinline__ void merge2(float (&a)[V], float (&b)[V],
                                       int lane) {
  {
    constexpr int LM = 2 * KB - 1;
    const float cdir = (lane & KB) ? INFINITY : -INFINITY;
#pragma unroll
    for (int q = 0; q < 4; ++q) {
      const int vA = 4 * q;
      float o[8];
#pragma unroll
      for (int u = 0; u < 4; ++u) {
        o[u]     = lane_xor<LM>(a[(vA + u) ^ 31]);
        o[u + 4] = lane_xor<LM>(a[vA + u]);
      }
#pragma unroll
      for (int u = 0; u < 4; ++u) {
        a[vA + u]        = ce_dir(a[vA + u],        o[u],     cdir);
        a[(vA + u) ^ 31] = ce_dir(a[(vA + u) ^ 31], o[u + 4], cdir);
      }
#pragma unroll
      for (int u = 0; u < 4; ++u) {
        o[u]     = lane_xor<LM>(b[(vA + u) ^ 31]);
        o[u + 4] = lane_xor<LM>(b[vA + u]);
      }
#pragma unroll
      for (int u = 0; u < 4; ++u) {
        b[vA + u]        = ce_dir(b[vA + u],        o[u],     cdir);
        b[(vA + u) ^ 31] = ce_dir(b[(vA + u) ^ 31], o[u + 4], cdir);
      }
    }
  }
  if constexpr (KB >= 32) {
    const float cd = (lane & 16) ? INFINITY : -INFINITY;
    xpass2<16>(a, b, cd);
  }
  if constexpr (KB >= 16) {
    const float cd = (lane & 8) ? INFINITY : -INFINITY;
    xpass2<8>(a, b, cd);
  }
  if constexpr (KB >= 8) {
    const float cd = (lane & 4) ? INFINITY : -INFINITY;
    xpass2<4>(a, b, cd);
  }
  if constexpr (KB >= 4) {
    const float cd = (lane & 2) ? INFINITY : -INFINITY;
    xpass2<2>(a, b, cd);
  }
  if constexpr (KB >= 2) {
    const float cd = (lane & 1) ? INFINITY : -INFINITY;
    xpass2<1>(a, b, cd);
  }
  // in-lane xor passes j = 16..1: static indices AND static direction
#pragma unroll
  for (int j = 16; j >= 1; j >>= 1) {
#pragma unroll
    for (int v = 0; v < V; ++v) {
      if ((v & j) == 0) {
        ce(a[v], a[v | j]);
        ce(b[v], b[v | j]);
      }
    }
  }
}

// One wave per row; lane holds elements e = lane*32 + v of both arrays in
// registers. Normalized bitonic sort (all compares ascending).
__global__ __launch_bounds__(THREADS, 4) void sort_mse_kernel(
    const float* __restrict__ pred, const float* __restrict__ targ,
    float* __restrict__ out) {
  const int lane = threadIdx.x & 63;
  const int wave = threadIdx.x >> 6;
  const int row = blockIdx.x * WPB + wave;
  const size_t base = (size_t)row * NCOL + (size_t)lane * V;

  float rp[V], rt[V];
  const float4* p4 = (const float4*)(pred + base);
  const float4* t4 = (const float4*)(targ + base);
#pragma unroll
  for (int q = 0; q < V / 4; ++q) {
    const float4 a = p4[q];
    rp[4 * q + 0] = a.x; rp[4 * q + 1] = a.y;
    rp[4 * q + 2] = a.z; rp[4 * q + 3] = a.w;
    const float4 b = t4[q];
    rt[4 * q + 0] = b.x; rt[4 * q + 1] = b.y;
    rt[4 * q + 2] = b.z; rt[4 * q + 3] = b.w;
  }

  // ---- Phase 1: stages k = 2..32, fully in-lane, fully static ----
#pragma unroll
  for (int k = 2; k <= V; k <<= 1) {
#pragma unroll
    for (int v = 0; v < V; ++v) {
      if ((v & (k >> 1)) == 0) {
        ce(rp[v], rp[v ^ (k - 1)]);
        ce(rt[v], rt[v ^ (k - 1)]);
      }
    }
#pragma unroll
    for (int j = k >> 2; j >= 1; j >>= 1) {
#pragma unroll
      for (int v = 0; v < V; ++v) {
        if ((v & j) == 0) {
          ce(rp[v], rp[v | j]);
          ce(rt[v], rt[v | j]);
        }
      }
    }
  }

  // ---- Phase 2: stages k = 64..2048 (KB = k/64 = 1..32) ----
  merge2<1>(rp, rt, lane);
  merge2<2>(rp, rt, lane);
  merge2<4>(rp, rt, lane);
  merge2<8>(rp, rt, lane);
  merge2<16>(rp, rt, lane);
  merge2<32>(rp, rt, lane);

  // ranks are matched at identical (lane, v) after both sorts
  float acc = 0.f;
#pragma unroll
  for (int v = 0; v < V; ++v) {
    const float d = rp[v] - rt[v];
    acc = fmaf(d, d, acc);
  }
#pragma unroll
  for (int off = 32; off > 0; off >>= 1) acc += __shfl_down(acc, off, 64);
  if (lane == 0) {
    unsafeAtomicAdd(out, acc * (1.0f / ((float)ROWS * (float)NCOL)));
  }
}

extern "C" void kernel_launch(void* const* d_in, const int* in_sizes, int n_in,
                              void* d_out, int out_size, void* d_ws, size_t ws_size,
                              hipStream_t stream) {
  const float* pred = (const float*)d_in[0];
  const float* targ = (const float*)d_in[1];
  float* out = (float*)d_out;

  hipMemsetAsync(out, 0, sizeof(float), stream);  // d_out is re-poisoned 0xAA
  sort_mse_kernel<<<ROWS / WPB, THREADS, 0, stream>>>(pred, targ, out);
}